// Round 9
// baseline (236.905 us; speedup 1.0000x reference)
//
#include <hip/hip_runtime.h>

#define K_CLUSTERS 512
#define D_FEAT 64
#define ROWS_PER_BLOCK 64
#define THREADS 256

typedef short bf16x8 __attribute__((ext_vector_type(8)));
typedef short bf16x4 __attribute__((ext_vector_type(4)));
typedef float f32x4 __attribute__((ext_vector_type(4)));

__device__ __forceinline__ unsigned short f32_to_bf16(float f) {
  unsigned int u = __float_as_uint(f);
  u += 0x7fffu + ((u >> 16) & 1u);   // RNE
  return (unsigned short)(u >> 16);
}
__device__ __forceinline__ unsigned short f32_to_bf16_trunc(float f) {
  return (unsigned short)(__float_as_uint(f) >> 16);
}
__device__ __forceinline__ unsigned short f32_to_bf16_rhu(float f) {
  return (unsigned short)((__float_as_uint(f) + 0x8000u) >> 16);
}
__device__ __forceinline__ float bf16_to_f32(unsigned short h) {
  return __uint_as_float(((unsigned int)h) << 16);
}

// W swizzle: element cx = cc ^ ((row&7)<<3), cc in [0,256).
#define WSWZ(row) ((((unsigned)(row)) & 7u) << 3)

// ---------------- prep: one wave per cluster, lane = feature. Coalesced.
__global__ void kmeans_prep(const float* __restrict__ cent,
                            unsigned short* __restrict__ chi,   // [K][D]
                            unsigned short* __restrict__ clo,   // [K][D]
                            unsigned short* __restrict__ cthi,  // [D][K]
                            unsigned short* __restrict__ ctlo,  // [D][K]
                            float* __restrict__ csqs) {         // [K], 10*log2e*|c|^2
  const int wv = threadIdx.x >> 6;
  const int lane = threadIdx.x & 63;
  const int k = blockIdx.x * 4 + wv;
  const int f = lane;
  float v = cent[k * D_FEAT + f];
  unsigned short h = f32_to_bf16_trunc(v);
  float rem = v - bf16_to_f32(h);
  unsigned short l = f32_to_bf16(rem);
  chi[k * D_FEAT + f] = h;
  clo[k * D_FEAT + f] = l;
  cthi[f * K_CLUSTERS + k] = h;
  ctlo[f * K_CLUSTERS + k] = l;
  float s = v * v;
#pragma unroll
  for (int d = 1; d < 64; d <<= 1) s += __shfl_xor(s, d, 64);
  if (lane == 0) csqs[k] = s * 14.42695040888963f;  // 10 * log2(e)
}

// ---------------- main: R5 structure, cluster-chunked W for 3 blocks/CU.
// K split in 2 chunks of 256: W[64][256] = 32KB; xh/xl DEDICATED (18KB, no
// alias) so A-frags load once and survive. LDS 51200 -> 3 blocks/CU
// (12 waves/CU, +50% vs R5's 2 blocks) at UNCHANGED per-wave ILP: this is
// the occupancy-at-constant-ILP experiment R2/R3/R4 each botched (ILP halved
// / spilled). launch_bounds 2nd arg == min BLOCKS/CU on this toolchain
// (R3: (512,4)->cap64; R4: (512,2)->cap128): (256,3) -> VGPR cap 170.
// Sequence: stage -> B1 -> frags -> A(0) -> B2 -> C(0) -> B3 -> A(1) -> B4
// -> C(1) -> epilogue. oh/ol/os accumulate across chunks; row sums via
// ones-B MFMA (R5, layout-aligned, absmax-improving).
__global__ __launch_bounds__(THREADS, 3) void kmeans_main(
    const float* __restrict__ x,
    const unsigned short* __restrict__ chi,
    const unsigned short* __restrict__ clo,
    const unsigned short* __restrict__ cthi,
    const unsigned short* __restrict__ ctlo,
    const float* __restrict__ csqs,
    float* __restrict__ out) {
  __shared__ __attribute__((aligned(16))) unsigned short xh[64 * 72];   // 9216 B
  __shared__ __attribute__((aligned(16))) unsigned short xl[64 * 72];   // 9216 B
  __shared__ __attribute__((aligned(16))) unsigned short W[64 * 256];   // 32768 B

  const int tid  = threadIdx.x;
  const int wv   = tid >> 6;
  const int lane = tid & 63;
  const int l16  = lane & 15;
  const int quad = lane >> 4;
  const long long rowbase = (long long)blockIdx.x * ROWS_PER_BLOCK;

  // ---- stage x -> xh/xl (coalesced float4 loads, hi=trunc/lo=RNE split) ----
  {
    int r  = tid >> 2;             // 0..63
    int f0 = (tid & 3) * 16;       // 0,16,32,48
    const float4* src4 = (const float4*)(x + (rowbase + r) * D_FEAT + f0);
#pragma unroll
    for (int i = 0; i < 4; ++i) {
      float4 v = src4[i];
      float vv[4] = {v.x, v.y, v.z, v.w};
      bf16x4 hi, lo;
#pragma unroll
      for (int j = 0; j < 4; ++j) {
        unsigned short h = f32_to_bf16_trunc(vv[j]);
        hi[j] = (short)h;
        lo[j] = (short)f32_to_bf16(vv[j] - bf16_to_f32(h));
      }
      *(bf16x4*)(xh + r * 72 + f0 + i * 4) = hi;
      *(bf16x4*)(xl + r * 72 + f0 + i * 4) = lo;
    }
  }
  __syncthreads();   // B1: staging visible (xh/xl persist; no aliasing)

  // ---- A fragments, loaded ONCE: A[m=l16][k=quad*8+j] ----
  bf16x8 ah[4][2], al[4][2];
#pragma unroll
  for (int rt = 0; rt < 4; ++rt)
#pragma unroll
    for (int ks = 0; ks < 2; ++ks) {
      ah[rt][ks] = *(const bf16x8*)(xh + (rt * 16 + l16) * 72 + ks * 32 + quad * 8);
      al[rt][ks] = *(const bf16x8*)(xl + (rt * 16 + l16) * 72 + ks * 32 + quad * 8);
    }

  const int feat = wv * 16 + l16;
  const unsigned short* cth = cthi + feat * K_CLUSTERS;
  const unsigned short* ctl = ctlo + feat * K_CLUSTERS;
  bf16x8 ones;
#pragma unroll
  for (int j = 0; j < 8; ++j) ones[j] = (short)0x3F80;

  f32x4 oh[4] = {{0.f,0.f,0.f,0.f},{0.f,0.f,0.f,0.f},{0.f,0.f,0.f,0.f},{0.f,0.f,0.f,0.f}};
  f32x4 ol[4] = {{0.f,0.f,0.f,0.f},{0.f,0.f,0.f,0.f},{0.f,0.f,0.f,0.f},{0.f,0.f,0.f,0.f}};
  f32x4 os[4] = {{0.f,0.f,0.f,0.f},{0.f,0.f,0.f,0.f},{0.f,0.f,0.f,0.f},{0.f,0.f,0.f,0.f}};

  const int bko = quad * 8;

#pragma unroll
  for (int ch = 0; ch < 2; ++ch) {
    // ---- Phase A(ch): wave's 64-cluster slice of this 256-chunk ----
    const int cbase = ch * 256 + wv * 64;   // global cluster base for this wave
    bf16x8 pbh0[2], pbh1[2], pbl0[2], pbl1[2];
    float pcs[2];
#pragma unroll
    for (int p = 0; p < 2; ++p) {
      int cl = cbase + p * 16 + l16;
      pbh0[p] = *(const bf16x8*)(chi + cl * 64 + bko);
      pbh1[p] = *(const bf16x8*)(chi + cl * 64 + 32 + bko);
      pbl0[p] = *(const bf16x8*)(clo + cl * 64 + bko);
      pbl1[p] = *(const bf16x8*)(clo + cl * 64 + 32 + bko);
      pcs[p]  = csqs[cl];
    }
#pragma unroll
    for (int t = 0; t < 4; ++t) {
      const int sl = t & 1;
      bf16x8 cbh0 = pbh0[sl], cbh1 = pbh1[sl], cbl0 = pbl0[sl], cbl1 = pbl1[sl];
      float ccs = pcs[sl];
      if (t < 2) {   // prefetch t+2
        int cl = cbase + (t + 2) * 16 + l16;
        pbh0[sl] = *(const bf16x8*)(chi + cl * 64 + bko);
        pbh1[sl] = *(const bf16x8*)(chi + cl * 64 + 32 + bko);
        pbl0[sl] = *(const bf16x8*)(clo + cl * 64 + bko);
        pbl1[sl] = *(const bf16x8*)(clo + cl * 64 + 32 + bko);
        pcs[sl]  = csqs[cl];
      }
      const int ccl = wv * 64 + t * 16 + l16;   // within-chunk column [0,256)
#pragma unroll
      for (int rt = 0; rt < 4; ++rt) {
        f32x4 a_hi = {0.f, 0.f, 0.f, 0.f};
        f32x4 a_lo = {0.f, 0.f, 0.f, 0.f};
        a_hi = __builtin_amdgcn_mfma_f32_16x16x32_bf16(ah[rt][0], cbh0, a_hi, 0, 0, 0);
        a_lo = __builtin_amdgcn_mfma_f32_16x16x32_bf16(al[rt][0], cbh0, a_lo, 0, 0, 0);
        a_hi = __builtin_amdgcn_mfma_f32_16x16x32_bf16(ah[rt][1], cbh1, a_hi, 0, 0, 0);
        a_lo = __builtin_amdgcn_mfma_f32_16x16x32_bf16(al[rt][1], cbh1, a_lo, 0, 0, 0);
        a_hi = __builtin_amdgcn_mfma_f32_16x16x32_bf16(ah[rt][0], cbl0, a_hi, 0, 0, 0);
        a_hi = __builtin_amdgcn_mfma_f32_16x16x32_bf16(ah[rt][1], cbl1, a_hi, 0, 0, 0);
        f32x4 a = a_hi + a_lo;
#pragma unroll
        for (int r = 0; r < 4; ++r) {
          float e = exp2f(fmaf(28.85390081777927f, a[r], -ccs));
          int row = rt * 16 + quad * 4 + r;
          W[row * 256 + ((unsigned)ccl ^ WSWZ(row))] = f32_to_bf16_rhu(e);
        }
      }
    }

    // ---- Phase C(ch) B prefetch issued before the barrier ----
    bf16x8 qbh[2], qbl[2];
#pragma unroll
    for (int p = 0; p < 2; ++p) {
      qbh[p] = *(const bf16x8*)(cth + ch * 256 + p * 32 + quad * 8);
      qbl[p] = *(const bf16x8*)(ctl + ch * 256 + p * 32 + quad * 8);
    }
    __syncthreads();   // B2/B4: all waves' W writes visible

    // ---- Phase C(ch): wave's 16-feature slice, 256 clusters, depth-2 ----
#pragma unroll
    for (int ksl = 0; ksl < 8; ++ksl) {
      const int sl = ksl & 1;
      bf16x8 bh = qbh[sl], bl = qbl[sl];
      if (ksl < 6) {   // prefetch ksl+2
        qbh[sl] = *(const bf16x8*)(cth + ch * 256 + (ksl + 2) * 32 + quad * 8);
        qbl[sl] = *(const bf16x8*)(ctl + ch * 256 + (ksl + 2) * 32 + quad * 8);
      }
      const int ac = ksl * 32 + quad * 8;   // within-chunk
      bf16x8 aw[4];
#pragma unroll
      for (int rt = 0; rt < 4; ++rt) {
        int arow = rt * 16 + l16;
        aw[rt] = *(const bf16x8*)(W + arow * 256 + ((unsigned)ac ^ WSWZ(arow)));
      }
#pragma unroll
      for (int rt = 0; rt < 4; ++rt) {
        oh[rt] = __builtin_amdgcn_mfma_f32_16x16x32_bf16(aw[rt], bh, oh[rt], 0, 0, 0);
        ol[rt] = __builtin_amdgcn_mfma_f32_16x16x32_bf16(aw[rt], bl, ol[rt], 0, 0, 0);
        os[rt] = __builtin_amdgcn_mfma_f32_16x16x32_bf16(aw[rt], ones, os[rt], 0, 0, 0);
      }
    }
    if (ch == 0) __syncthreads();   // B3: C(0) reads done before A(1) rewrites W
  }

  // ---- epilogue: normalize by MFMA row sums (layout-aligned, no shuffles) ----
#pragma unroll
  for (int rt = 0; rt < 4; ++rt) {
    float* obase = out + (rowbase + rt * 16) * D_FEAT + feat;
#pragma unroll
    for (int r = 0; r < 4; ++r) {
      float val = (oh[rt][r] + ol[rt][r]) * __builtin_amdgcn_rcpf(os[rt][r]);
      obase[(quad * 4 + r) * D_FEAT] = val;
    }
  }
}

extern "C" void kernel_launch(void* const* d_in, const int* in_sizes, int n_in,
                              void* d_out, int out_size, void* d_ws, size_t ws_size,
                              hipStream_t stream) {
  const float* x    = (const float*)d_in[0];
  const float* cent = (const float*)d_in[1];
  float* out        = (float*)d_out;

  unsigned short* chi  = (unsigned short*)d_ws;
  unsigned short* clo  = chi  + K_CLUSTERS * D_FEAT;
  unsigned short* cthi = clo  + K_CLUSTERS * D_FEAT;
  unsigned short* ctlo = cthi + K_CLUSTERS * D_FEAT;
  float*          csqs = (float*)(ctlo + K_CLUSTERS * D_FEAT);

  kmeans_prep<<<K_CLUSTERS / 4, 256, 0, stream>>>(
      cent, chi, clo, cthi, ctlo, csqs);

  int nrows = in_sizes[0] / D_FEAT;  // 131072
  kmeans_main<<<nrows / ROWS_PER_BLOCK, THREADS, 0, stream>>>(
      x, chi, clo, cthi, ctlo, csqs, out);
}

// Round 10
// 129.935 us; speedup vs baseline: 1.8233x; 1.8233x over previous
//
#include <hip/hip_runtime.h>

#define K_CLUSTERS 512
#define D_FEAT 64
#define ROWS_PER_BLOCK 64
#define THREADS 256

typedef short bf16x8 __attribute__((ext_vector_type(8)));
typedef short bf16x4 __attribute__((ext_vector_type(4)));
typedef float f32x4 __attribute__((ext_vector_type(4)));

__device__ __forceinline__ unsigned short f32_to_bf16(float f) {
  unsigned int u = __float_as_uint(f);
  u += 0x7fffu + ((u >> 16) & 1u);   // RNE
  return (unsigned short)(u >> 16);
}
__device__ __forceinline__ unsigned short f32_to_bf16_trunc(float f) {
  return (unsigned short)(__float_as_uint(f) >> 16);
}
__device__ __forceinline__ unsigned short f32_to_bf16_rhu(float f) {
  return (unsigned short)((__float_as_uint(f) + 0x8000u) >> 16);
}
__device__ __forceinline__ float bf16_to_f32(unsigned short h) {
  return __uint_as_float(((unsigned int)h) << 16);
}

// W swizzle: element cx = c ^ ((row&7)<<3).
#define WSWZ(row) ((((unsigned)(row)) & 7u) << 3)

// ---------------- prep: one wave per cluster, lane = feature. Coalesced.
__global__ void kmeans_prep(const float* __restrict__ cent,
                            unsigned short* __restrict__ chi,   // [K][D]
                            unsigned short* __restrict__ clo,   // [K][D]
                            unsigned short* __restrict__ cthi,  // [D][K]
                            float* __restrict__ csqs) {         // [K], 10*log2e*|c|^2
  const int wv = threadIdx.x >> 6;
  const int lane = threadIdx.x & 63;
  const int k = blockIdx.x * 4 + wv;
  const int f = lane;
  float v = cent[k * D_FEAT + f];
  unsigned short h = f32_to_bf16_trunc(v);
  float rem = v - bf16_to_f32(h);
  unsigned short l = f32_to_bf16(rem);
  chi[k * D_FEAT + f] = h;
  clo[k * D_FEAT + f] = l;
  // PV centroid: RNE-rounded full value (hi-only PV; see main comment)
  cthi[f * K_CLUSTERS + k] = f32_to_bf16(v);
  float s = v * v;
#pragma unroll
  for (int d = 1; d < 64; d <<= 1) s += __shfl_xor(s, d, 64);
  if (lane == 0) csqs[k] = s * 14.42695040888963f;  // 10 * log2(e)
}

// ---------------- main: R6 skeleton (80.4 us), minus provable excess work.
// Evidence through R9: occupancy >2 blocks/CU unreachable at full ILP
// (launch_bounds cap == 256/arg2 empirically: R3 64, R9 84, R4/R5 128);
// L2 BW not binding (R8 had half the traffic, 2x the time); micro-scheduling
// null (R5/R6). This round cuts certain work:
// (1) PV-lo dropped: hi-only (RNE) centroids in Phase C. -64 MFMA/wave
//     (-17%), -16 loads/thread, -128KB/block L2. Error adds <=2.3e-4
//     (weighted avg of RNE centroid quant) on 9.8e-4 -> ~0.0012 < pass level.
// (2) Phase A: all 24 MFMAs batched before the 16-exp VALU tail (bigger
//     homogeneous bursts for cross-wave pipe overlap).
// Row sums stay on MFMA (ones-B os; VALU is the busier pipe).
__global__ __launch_bounds__(THREADS, 2) void kmeans_main(
    const float* __restrict__ x,
    const unsigned short* __restrict__ chi,
    const unsigned short* __restrict__ clo,
    const unsigned short* __restrict__ cthi,
    const float* __restrict__ csqs,
    float* __restrict__ out) {
  // LDS: W [64][512] bf16 (65536 B, swizzled). x staging xh/xl [64][72]
  // aliases head of W (dead after A-frag loads, fenced by barrier 2).
  __shared__ __attribute__((aligned(16))) unsigned char smem[65536];
  unsigned short* xh = (unsigned short*)smem;            // [64][72]
  unsigned short* xl = xh + 64 * 72;                     // [64][72]
  unsigned short* W  = (unsigned short*)smem;            // [64][512] swizzled

  const int tid  = threadIdx.x;
  const int wv   = tid >> 6;
  const int lane = tid & 63;
  const int l16  = lane & 15;
  const int quad = lane >> 4;
  const long long rowbase = (long long)blockIdx.x * ROWS_PER_BLOCK;

  // ---- stage x -> xh/xl (coalesced float4 loads, hi=trunc/lo=RNE split) ----
  {
    int r  = tid >> 2;             // 0..63
    int f0 = (tid & 3) * 16;       // 0,16,32,48
    const float4* src4 = (const float4*)(x + (rowbase + r) * D_FEAT + f0);
#pragma unroll
    for (int i = 0; i < 4; ++i) {
      float4 v = src4[i];
      float vv[4] = {v.x, v.y, v.z, v.w};
      bf16x4 hi, lo;
#pragma unroll
      for (int j = 0; j < 4; ++j) {
        unsigned short h = f32_to_bf16_trunc(vv[j]);
        hi[j] = (short)h;
        lo[j] = (short)f32_to_bf16(vv[j] - bf16_to_f32(h));
      }
      *(bf16x4*)(xh + r * 72 + f0 + i * 4) = hi;
      *(bf16x4*)(xl + r * 72 + f0 + i * 4) = lo;
    }
  }
  __syncthreads();   // staging visible

  // ---- A fragments: A[m=l16][k=quad*8+j] ----
  bf16x8 ah[4][2], al[4][2];
#pragma unroll
  for (int rt = 0; rt < 4; ++rt)
#pragma unroll
    for (int ks = 0; ks < 2; ++ks) {
      ah[rt][ks] = *(const bf16x8*)(xh + (rt * 16 + l16) * 72 + ks * 32 + quad * 8);
      al[rt][ks] = *(const bf16x8*)(xl + (rt * 16 + l16) * 72 + ks * 32 + quad * 8);
    }
  __syncthreads();   // xh/xl dead -> W region writable

  // ---- Phase A: wave's 128-cluster slice x 64 rows, depth-2 prefetch ----
  const int cbase = wv * 128;
  const int bko = quad * 8;

  bf16x8 pbh0[2], pbh1[2], pbl0[2], pbl1[2];
  float pcs[2];
#pragma unroll
  for (int p = 0; p < 2; ++p) {
    int cl = cbase + p * 16 + l16;
    pbh0[p] = *(const bf16x8*)(chi + cl * 64 + bko);
    pbh1[p] = *(const bf16x8*)(chi + cl * 64 + 32 + bko);
    pbl0[p] = *(const bf16x8*)(clo + cl * 64 + bko);
    pbl1[p] = *(const bf16x8*)(clo + cl * 64 + 32 + bko);
    pcs[p]  = csqs[cl];
  }

#pragma unroll
  for (int t = 0; t < 8; ++t) {
    const int sl = t & 1;
    bf16x8 cbh0 = pbh0[sl], cbh1 = pbh1[sl], cbl0 = pbl0[sl], cbl1 = pbl1[sl];
    float ccs = pcs[sl];
    if (t < 6) {   // prefetch t+2
      int cl = cbase + (t + 2) * 16 + l16;
      pbh0[sl] = *(const bf16x8*)(chi + cl * 64 + bko);
      pbh1[sl] = *(const bf16x8*)(chi + cl * 64 + 32 + bko);
      pbl0[sl] = *(const bf16x8*)(clo + cl * 64 + bko);
      pbl1[sl] = *(const bf16x8*)(clo + cl * 64 + 32 + bko);
      pcs[sl]  = csqs[cl];
    }
    const int c = cbase + t * 16 + l16;
    // (2) all 24 MFMAs first (4 rt x 6, split a_hi||a_lo chains), then exp tail
    f32x4 av[4];
#pragma unroll
    for (int rt = 0; rt < 4; ++rt) {
      f32x4 a_hi = {0.f, 0.f, 0.f, 0.f};
      f32x4 a_lo = {0.f, 0.f, 0.f, 0.f};
      a_hi = __builtin_amdgcn_mfma_f32_16x16x32_bf16(ah[rt][0], cbh0, a_hi, 0, 0, 0);
      a_lo = __builtin_amdgcn_mfma_f32_16x16x32_bf16(al[rt][0], cbh0, a_lo, 0, 0, 0);
      a_hi = __builtin_amdgcn_mfma_f32_16x16x32_bf16(ah[rt][1], cbh1, a_hi, 0, 0, 0);
      a_lo = __builtin_amdgcn_mfma_f32_16x16x32_bf16(al[rt][1], cbh1, a_lo, 0, 0, 0);
      a_hi = __builtin_amdgcn_mfma_f32_16x16x32_bf16(ah[rt][0], cbl0, a_hi, 0, 0, 0);
      a_hi = __builtin_amdgcn_mfma_f32_16x16x32_bf16(ah[rt][1], cbl1, a_hi, 0, 0, 0);
      av[rt] = a_hi + a_lo;
    }
#pragma unroll
    for (int rt = 0; rt < 4; ++rt)
#pragma unroll
      for (int r = 0; r < 4; ++r) {
        float e = exp2f(fmaf(28.85390081777927f, av[rt][r], -ccs));
        int row = rt * 16 + quad * 4 + r;
        W[row * 512 + ((unsigned)c ^ WSWZ(row))] = f32_to_bf16_rhu(e);
      }
  }

  // ---- Phase C B prefetch, depth 4, issued before the barrier ----
  const int feat = wv * 16 + l16;
  const unsigned short* cth = cthi + feat * K_CLUSTERS;
  bf16x8 qbh[4];
#pragma unroll
  for (int p = 0; p < 4; ++p)
    qbh[p] = *(const bf16x8*)(cth + p * 32 + quad * 8);
  bf16x8 ones;
#pragma unroll
  for (int j = 0; j < 8; ++j) ones[j] = (short)0x3F80;

  __syncthreads();   // W visible to all waves

  // ---- Phase C: wave's 16-feature slice, full K=512, hi-only PV.
  // 8 independent chains: oh[4] (W*C), os[4] (row sums via ones-B).
  f32x4 oh[4] = {{0.f,0.f,0.f,0.f},{0.f,0.f,0.f,0.f},{0.f,0.f,0.f,0.f},{0.f,0.f,0.f,0.f}};
  f32x4 os[4] = {{0.f,0.f,0.f,0.f},{0.f,0.f,0.f,0.f},{0.f,0.f,0.f,0.f},{0.f,0.f,0.f,0.f}};

#pragma unroll
  for (int ks = 0; ks < 16; ++ks) {
    const int sl = ks & 3;
    bf16x8 bh = qbh[sl];
    if (ks < 12)   // prefetch ks+4
      qbh[sl] = *(const bf16x8*)(cth + (ks + 4) * 32 + quad * 8);
    const int ac = ks * 32 + quad * 8;
    bf16x8 aw[4];
#pragma unroll
    for (int rt = 0; rt < 4; ++rt) {
      int arow = rt * 16 + l16;
      aw[rt] = *(const bf16x8*)(W + arow * 512 + ((unsigned)ac ^ WSWZ(arow)));
    }
#pragma unroll
    for (int rt = 0; rt < 4; ++rt) {
      oh[rt] = __builtin_amdgcn_mfma_f32_16x16x32_bf16(aw[rt], bh, oh[rt], 0, 0, 0);
      os[rt] = __builtin_amdgcn_mfma_f32_16x16x32_bf16(aw[rt], ones, os[rt], 0, 0, 0);
    }
  }

  // ---- epilogue: normalize by MFMA row sums (layout-aligned, no shuffles) ----
#pragma unroll
  for (int rt = 0; rt < 4; ++rt) {
    float* obase = out + (rowbase + rt * 16) * D_FEAT + feat;
#pragma unroll
    for (int r = 0; r < 4; ++r) {
      float val = oh[rt][r] * __builtin_amdgcn_rcpf(os[rt][r]);
      obase[(quad * 4 + r) * D_FEAT] = val;
    }
  }
}

extern "C" void kernel_launch(void* const* d_in, const int* in_sizes, int n_in,
                              void* d_out, int out_size, void* d_ws, size_t ws_size,
                              hipStream_t stream) {
  const float* x    = (const float*)d_in[0];
  const float* cent = (const float*)d_in[1];
  float* out        = (float*)d_out;

  unsigned short* chi  = (unsigned short*)d_ws;
  unsigned short* clo  = chi  + K_CLUSTERS * D_FEAT;
  unsigned short* cthi = clo  + K_CLUSTERS * D_FEAT;
  float*          csqs = (float*)(cthi + K_CLUSTERS * D_FEAT);

  kmeans_prep<<<K_CLUSTERS / 4, 256, 0, stream>>>(
      cent, chi, clo, cthi, csqs);

  int nrows = in_sizes[0] / D_FEAT;  // 131072
  kmeans_main<<<nrows / ROWS_PER_BLOCK, THREADS, 0, stream>>>(
      x, chi, clo, cthi, csqs, out);
}

// Round 11
// 128.880 us; speedup vs baseline: 1.8382x; 1.0082x over previous
//
#include <hip/hip_runtime.h>

#define K_CLUSTERS 512
#define D_FEAT 64
#define ROWS_PER_BLOCK 64
#define THREADS 256

typedef short bf16x8 __attribute__((ext_vector_type(8)));
typedef short bf16x4 __attribute__((ext_vector_type(4)));
typedef float f32x4 __attribute__((ext_vector_type(4)));

__device__ __forceinline__ unsigned short f32_to_bf16(float f) {
  unsigned int u = __float_as_uint(f);
  u += 0x7fffu + ((u >> 16) & 1u);   // RNE
  return (unsigned short)(u >> 16);
}
__device__ __forceinline__ unsigned short f32_to_bf16_trunc(float f) {
  return (unsigned short)(__float_as_uint(f) >> 16);
}
__device__ __forceinline__ unsigned short f32_to_bf16_rhu(float f) {
  return (unsigned short)((__float_as_uint(f) + 0x8000u) >> 16);
}
__device__ __forceinline__ float bf16_to_f32(unsigned short h) {
  return __uint_as_float(((unsigned int)h) << 16);
}

// W swizzle: element cx = c ^ ((row&7)<<3).
#define WSWZ(row) ((((unsigned)(row)) & 7u) << 3)

// ---------------- prep: one wave per cluster, lane = feature. Coalesced.
__global__ void kmeans_prep(const float* __restrict__ cent,
                            unsigned short* __restrict__ chi,   // [K][D]
                            unsigned short* __restrict__ clo,   // [K][D]
                            unsigned short* __restrict__ cthi,  // [D][K]
                            float* __restrict__ csqs) {         // [K], 10*log2e*|c|^2
  const int wv = threadIdx.x >> 6;
  const int lane = threadIdx.x & 63;
  const int k = blockIdx.x * 4 + wv;
  const int f = lane;
  float v = cent[k * D_FEAT + f];
  unsigned short h = f32_to_bf16_trunc(v);
  float rem = v - bf16_to_f32(h);
  unsigned short l = f32_to_bf16(rem);
  chi[k * D_FEAT + f] = h;
  clo[k * D_FEAT + f] = l;
  // PV centroid: RNE-rounded full value (hi-only PV, R10)
  cthi[f * K_CLUSTERS + k] = f32_to_bf16(v);
  float s = v * v;
#pragma unroll
  for (int d = 1; d < 64; d <<= 1) s += __shfl_xor(s, d, 64);
  if (lane == 0) csqs[k] = s * 14.42695040888963f;  // 10 * log2(e)
}

// ---------------- main: R10 skeleton + swapped Phase-A MFMA operands.
// mfma(cent, x) instead of mfma(x, cent): A/B frags have identical per-lane
// layouts, so this is argument order only (bit-identical dot products). D
// becomes [cluster][row]: each acc quad = 4 CONSECUTIVE clusters x 1 row ->
// the 4 exp'd weights pack to one bf16x4 and store via ONE ds_write_b64
// (swizzle keeps them consecutive: swz is mult-of-8, c0 is 4-aligned).
// Replaces 16 scattered ds_write_b16 + 16 addr calcs per t-step with 4+4.
// csq moves from lane-keyed scalar to per-t f32x4 (cluster = c0 + r now).
// Everything else identical to R10 (hi-only PV, ones-B row sums, depth-4
// Phase-C prefetch, batched aw reads, launch_bounds(256,2) -> cap 128).
__global__ __launch_bounds__(THREADS, 2) void kmeans_main(
    const float* __restrict__ x,
    const unsigned short* __restrict__ chi,
    const unsigned short* __restrict__ clo,
    const unsigned short* __restrict__ cthi,
    const float* __restrict__ csqs,
    float* __restrict__ out) {
  // LDS: W [64][512] bf16 (65536 B, swizzled). x staging xh/xl [64][72]
  // aliases head of W (dead after A-frag loads, fenced by barrier 2).
  __shared__ __attribute__((aligned(16))) unsigned char smem[65536];
  unsigned short* xh = (unsigned short*)smem;            // [64][72]
  unsigned short* xl = xh + 64 * 72;                     // [64][72]
  unsigned short* W  = (unsigned short*)smem;            // [64][512] swizzled

  const int tid  = threadIdx.x;
  const int wv   = tid >> 6;
  const int lane = tid & 63;
  const int l16  = lane & 15;
  const int quad = lane >> 4;
  const long long rowbase = (long long)blockIdx.x * ROWS_PER_BLOCK;

  // ---- stage x -> xh/xl (coalesced float4 loads, hi=trunc/lo=RNE split) ----
  {
    int r  = tid >> 2;             // 0..63
    int f0 = (tid & 3) * 16;       // 0,16,32,48
    const float4* src4 = (const float4*)(x + (rowbase + r) * D_FEAT + f0);
#pragma unroll
    for (int i = 0; i < 4; ++i) {
      float4 v = src4[i];
      float vv[4] = {v.x, v.y, v.z, v.w};
      bf16x4 hi, lo;
#pragma unroll
      for (int j = 0; j < 4; ++j) {
        unsigned short h = f32_to_bf16_trunc(vv[j]);
        hi[j] = (short)h;
        lo[j] = (short)f32_to_bf16(vv[j] - bf16_to_f32(h));
      }
      *(bf16x4*)(xh + r * 72 + f0 + i * 4) = hi;
      *(bf16x4*)(xl + r * 72 + f0 + i * 4) = lo;
    }
  }
  __syncthreads();   // staging visible

  // ---- x fragments: per-lane 8 feats of row (rt*16+l16), k=quad*8+j ----
  bf16x8 ah[4][2], al[4][2];
#pragma unroll
  for (int rt = 0; rt < 4; ++rt)
#pragma unroll
    for (int ks = 0; ks < 2; ++ks) {
      ah[rt][ks] = *(const bf16x8*)(xh + (rt * 16 + l16) * 72 + ks * 32 + quad * 8);
      al[rt][ks] = *(const bf16x8*)(xl + (rt * 16 + l16) * 72 + ks * 32 + quad * 8);
    }
  __syncthreads();   // xh/xl dead -> W region writable

  // ---- Phase A: wave's 128-cluster slice x 64 rows, depth-2 prefetch ----
  const int cbase = wv * 128;
  const int bko = quad * 8;

  bf16x8 pbh0[2], pbh1[2], pbl0[2], pbl1[2];
  f32x4 pcs4[2];
#pragma unroll
  for (int p = 0; p < 2; ++p) {
    int cl = cbase + p * 16 + l16;
    pbh0[p] = *(const bf16x8*)(chi + cl * 64 + bko);
    pbh1[p] = *(const bf16x8*)(chi + cl * 64 + 32 + bko);
    pbl0[p] = *(const bf16x8*)(clo + cl * 64 + bko);
    pbl1[p] = *(const bf16x8*)(clo + cl * 64 + 32 + bko);
    pcs4[p] = *(const f32x4*)(csqs + cbase + p * 16 + quad * 4);
  }

  const unsigned swz = ((unsigned)(l16 & 7)) << 3;   // row&7 == l16&7 (rows rt*16+l16)

#pragma unroll
  for (int t = 0; t < 8; ++t) {
    const int sl = t & 1;
    bf16x8 cbh0 = pbh0[sl], cbh1 = pbh1[sl], cbl0 = pbl0[sl], cbl1 = pbl1[sl];
    f32x4 csq4 = pcs4[sl];
    if (t < 6) {   // prefetch t+2
      int cl = cbase + (t + 2) * 16 + l16;
      pbh0[sl] = *(const bf16x8*)(chi + cl * 64 + bko);
      pbh1[sl] = *(const bf16x8*)(chi + cl * 64 + 32 + bko);
      pbl0[sl] = *(const bf16x8*)(clo + cl * 64 + bko);
      pbl1[sl] = *(const bf16x8*)(clo + cl * 64 + 32 + bko);
      pcs4[sl] = *(const f32x4*)(csqs + cbase + (t + 2) * 16 + quad * 4);
    }
    const int c0 = cbase + t * 16 + quad * 4;
    // 24 MFMAs (swapped operands: D[m=cluster(quad*4+r)][n=row(l16)])
    f32x4 av[4];
#pragma unroll
    for (int rt = 0; rt < 4; ++rt) {
      f32x4 a_hi = {0.f, 0.f, 0.f, 0.f};
      f32x4 a_lo = {0.f, 0.f, 0.f, 0.f};
      a_hi = __builtin_amdgcn_mfma_f32_16x16x32_bf16(cbh0, ah[rt][0], a_hi, 0, 0, 0);
      a_lo = __builtin_amdgcn_mfma_f32_16x16x32_bf16(cbh0, al[rt][0], a_lo, 0, 0, 0);
      a_hi = __builtin_amdgcn_mfma_f32_16x16x32_bf16(cbh1, ah[rt][1], a_hi, 0, 0, 0);
      a_lo = __builtin_amdgcn_mfma_f32_16x16x32_bf16(cbh1, al[rt][1], a_lo, 0, 0, 0);
      a_hi = __builtin_amdgcn_mfma_f32_16x16x32_bf16(cbl0, ah[rt][0], a_hi, 0, 0, 0);
      a_hi = __builtin_amdgcn_mfma_f32_16x16x32_bf16(cbl1, ah[rt][1], a_hi, 0, 0, 0);
      av[rt] = a_hi + a_lo;
    }
    // exp tail + packed b64 stores (4 consecutive clusters, 1 row per rt)
#pragma unroll
    for (int rt = 0; rt < 4; ++rt) {
      bf16x4 wp;
#pragma unroll
      for (int r = 0; r < 4; ++r) {
        float e = exp2f(fmaf(28.85390081777927f, av[rt][r], -csq4[r]));
        wp[r] = (short)f32_to_bf16_rhu(e);
      }
      *(bf16x4*)(W + (rt * 16 + l16) * 512 + ((unsigned)c0 ^ swz)) = wp;
    }
  }

  // ---- Phase C B prefetch, depth 4, issued before the barrier ----
  const int feat = wv * 16 + l16;
  const unsigned short* cth = cthi + feat * K_CLUSTERS;
  bf16x8 qbh[4];
#pragma unroll
  for (int p = 0; p < 4; ++p)
    qbh[p] = *(const bf16x8*)(cth + p * 32 + quad * 8);
  bf16x8 ones;
#pragma unroll
  for (int j = 0; j < 8; ++j) ones[j] = (short)0x3F80;

  __syncthreads();   // W visible to all waves

  // ---- Phase C: wave's 16-feature slice, full K=512, hi-only PV.
  // 8 independent chains: oh[4] (W*C), os[4] (row sums via ones-B).
  f32x4 oh[4] = {{0.f,0.f,0.f,0.f},{0.f,0.f,0.f,0.f},{0.f,0.f,0.f,0.f},{0.f,0.f,0.f,0.f}};
  f32x4 os[4] = {{0.f,0.f,0.f,0.f},{0.f,0.f,0.f,0.f},{0.f,0.f,0.f,0.f},{0.f,0.f,0.f,0.f}};

#pragma unroll
  for (int ks = 0; ks < 16; ++ks) {
    const int sl = ks & 3;
    bf16x8 bh = qbh[sl];
    if (ks < 12)   // prefetch ks+4
      qbh[sl] = *(const bf16x8*)(cth + (ks + 4) * 32 + quad * 8);
    const int ac = ks * 32 + quad * 8;
    bf16x8 aw[4];
#pragma unroll
    for (int rt = 0; rt < 4; ++rt) {
      int arow = rt * 16 + l16;
      aw[rt] = *(const bf16x8*)(W + arow * 512 + ((unsigned)ac ^ WSWZ(arow)));
    }
#pragma unroll
    for (int rt = 0; rt < 4; ++rt) {
      oh[rt] = __builtin_amdgcn_mfma_f32_16x16x32_bf16(aw[rt], bh, oh[rt], 0, 0, 0);
      os[rt] = __builtin_amdgcn_mfma_f32_16x16x32_bf16(aw[rt], ones, os[rt], 0, 0, 0);
    }
  }

  // ---- epilogue: normalize by MFMA row sums (layout-aligned, no shuffles) ----
#pragma unroll
  for (int rt = 0; rt < 4; ++rt) {
    float* obase = out + (rowbase + rt * 16) * D_FEAT + feat;
#pragma unroll
    for (int r = 0; r < 4; ++r) {
      float val = oh[rt][r] * __builtin_amdgcn_rcpf(os[rt][r]);
      obase[(quad * 4 + r) * D_FEAT] = val;
    }
  }
}

extern "C" void kernel_launch(void* const* d_in, const int* in_sizes, int n_in,
                              void* d_out, int out_size, void* d_ws, size_t ws_size,
                              hipStream_t stream) {
  const float* x    = (const float*)d_in[0];
  const float* cent = (const float*)d_in[1];
  float* out        = (float*)d_out;

  unsigned short* chi  = (unsigned short*)d_ws;
  unsigned short* clo  = chi  + K_CLUSTERS * D_FEAT;
  unsigned short* cthi = clo  + K_CLUSTERS * D_FEAT;
  float*          csqs = (float*)(cthi + K_CLUSTERS * D_FEAT);

  kmeans_prep<<<K_CLUSTERS / 4, 256, 0, stream>>>(
      cent, chi, clo, cthi, csqs);

  int nrows = in_sizes[0] / D_FEAT;  // 131072
  kmeans_main<<<nrows / ROWS_PER_BLOCK, THREADS, 0, stream>>>(
      x, chi, clo, cthi, csqs, out);
}

// Round 12
// 127.282 us; speedup vs baseline: 1.8613x; 1.0126x over previous
//
#include <hip/hip_runtime.h>

#define K_CLUSTERS 512
#define D_FEAT 64
#define ROWS_PER_BLOCK 64
#define THREADS 256

typedef short bf16x8 __attribute__((ext_vector_type(8)));
typedef short bf16x4 __attribute__((ext_vector_type(4)));
typedef float f32x4 __attribute__((ext_vector_type(4)));

__device__ __forceinline__ unsigned short f32_to_bf16(float f) {
  unsigned int u = __float_as_uint(f);
  u += 0x7fffu + ((u >> 16) & 1u);   // RNE
  return (unsigned short)(u >> 16);
}
__device__ __forceinline__ unsigned short f32_to_bf16_trunc(float f) {
  return (unsigned short)(__float_as_uint(f) >> 16);
}
__device__ __forceinline__ float bf16_to_f32(unsigned short h) {
  return __uint_as_float(((unsigned int)h) << 16);
}
// raw 2^x — exact for |x| < ~126; our exponent is in [-50, 50] (see Phase A)
__device__ __forceinline__ float vexp2(float a) {
  float r;
  asm("v_exp_f32 %0, %1" : "=v"(r) : "v"(a));
  return r;
}
// packed RNE f32x2 -> bf16x2 (low = a, high = b); no builtin on gfx950
__device__ __forceinline__ unsigned cvtpk_bf16(float a, float b) {
  unsigned r;
  asm("v_cvt_pk_bf16_f32 %0, %1, %2" : "=v"(r) : "v"(a), "v"(b));
  return r;
}

// W swizzle: element cx = c ^ ((row&7)<<3).
#define WSWZ(row) ((((unsigned)(row)) & 7u) << 3)

// ---------------- prep: one wave per cluster, lane = feature. Coalesced.
__global__ void kmeans_prep(const float* __restrict__ cent,
                            unsigned short* __restrict__ chi,   // [K][D]
                            unsigned short* __restrict__ clo,   // [K][D]
                            unsigned short* __restrict__ cthi,  // [D][K]
                            float* __restrict__ csqs) {         // [K], 10*log2e*|c|^2
  const int wv = threadIdx.x >> 6;
  const int lane = threadIdx.x & 63;
  const int k = blockIdx.x * 4 + wv;
  const int f = lane;
  float v = cent[k * D_FEAT + f];
  unsigned short h = f32_to_bf16_trunc(v);
  float rem = v - bf16_to_f32(h);
  unsigned short l = f32_to_bf16(rem);
  chi[k * D_FEAT + f] = h;
  clo[k * D_FEAT + f] = l;
  // PV centroid: RNE-rounded full value (hi-only PV, R10)
  cthi[f * K_CLUSTERS + k] = f32_to_bf16(v);
  float s = v * v;
#pragma unroll
  for (int d = 1; d < 64; d <<= 1) s += __shfl_xor(s, d, 64);
  if (lane == 0) csqs[k] = s * 14.42695040888963f;  // 10 * log2(e)
}

// ---------------- main: R11 skeleton + VALU diet.
// R11 calibration: harness = rocprof_main + ~62us fixed; main = 67us with
// MFMA 17 / VALU 25 us-equiv busy. The VALU excess over algorithmic count
// is transcendental+convert expansion: ocml exp2f (range fixups) and 3-op
// RNE converts. Replaced with raw ISA ops, valid in our proven ranges:
// (1) v_exp_f32 for 2^x: exponent = 28.85*a - csq in [-50,50] -> no fixups
//     needed, result always normal.
// (2) v_cvt_pk_bf16_f32 (RNE, 1 op per PAIR) for W-pack and staging-lo pack.
// Everything else byte-identical to R11 (swapped-operand Phase A with b64
// W stores, hi-only PV, ones-B row sums, depth-4 C prefetch, (256,2)).
__global__ __launch_bounds__(THREADS, 2) void kmeans_main(
    const float* __restrict__ x,
    const unsigned short* __restrict__ chi,
    const unsigned short* __restrict__ clo,
    const unsigned short* __restrict__ cthi,
    const float* __restrict__ csqs,
    float* __restrict__ out) {
  // LDS: W [64][512] bf16 (65536 B, swizzled). x staging xh/xl [64][72]
  // aliases head of W (dead after A-frag loads, fenced by barrier 2).
  __shared__ __attribute__((aligned(16))) unsigned char smem[65536];
  unsigned short* xh = (unsigned short*)smem;            // [64][72]
  unsigned short* xl = xh + 64 * 72;                     // [64][72]
  unsigned short* W  = (unsigned short*)smem;            // [64][512] swizzled

  const int tid  = threadIdx.x;
  const int wv   = tid >> 6;
  const int lane = tid & 63;
  const int l16  = lane & 15;
  const int quad = lane >> 4;
  const long long rowbase = (long long)blockIdx.x * ROWS_PER_BLOCK;

  // ---- stage x -> xh/xl (float4 loads; hi=trunc pair-pack, lo=cvt_pk RNE) ----
  {
    int r  = tid >> 2;             // 0..63
    int f0 = (tid & 3) * 16;       // 0,16,32,48
    const float4* src4 = (const float4*)(x + (rowbase + r) * D_FEAT + f0);
#pragma unroll
    for (int i = 0; i < 4; ++i) {
      float4 v = src4[i];
      unsigned u0 = __float_as_uint(v.x), u1 = __float_as_uint(v.y);
      unsigned u2 = __float_as_uint(v.z), u3 = __float_as_uint(v.w);
      uint2 hp;
      hp.x = (u0 >> 16) | (u1 & 0xffff0000u);
      hp.y = (u2 >> 16) | (u3 & 0xffff0000u);
      float r0 = v.x - __uint_as_float(u0 & 0xffff0000u);
      float r1 = v.y - __uint_as_float(u1 & 0xffff0000u);
      float r2 = v.z - __uint_as_float(u2 & 0xffff0000u);
      float r3 = v.w - __uint_as_float(u3 & 0xffff0000u);
      uint2 lp;
      lp.x = cvtpk_bf16(r0, r1);
      lp.y = cvtpk_bf16(r2, r3);
      *(uint2*)(xh + r * 72 + f0 + i * 4) = hp;
      *(uint2*)(xl + r * 72 + f0 + i * 4) = lp;
    }
  }
  __syncthreads();   // staging visible

  // ---- x fragments: per-lane 8 feats of row (rt*16+l16), k=quad*8+j ----
  bf16x8 ah[4][2], al[4][2];
#pragma unroll
  for (int rt = 0; rt < 4; ++rt)
#pragma unroll
    for (int ks = 0; ks < 2; ++ks) {
      ah[rt][ks] = *(const bf16x8*)(xh + (rt * 16 + l16) * 72 + ks * 32 + quad * 8);
      al[rt][ks] = *(const bf16x8*)(xl + (rt * 16 + l16) * 72 + ks * 32 + quad * 8);
    }
  __syncthreads();   // xh/xl dead -> W region writable

  // ---- Phase A: wave's 128-cluster slice x 64 rows, depth-2 prefetch ----
  const int cbase = wv * 128;
  const int bko = quad * 8;

  bf16x8 pbh0[2], pbh1[2], pbl0[2], pbl1[2];
  f32x4 pcs4[2];
#pragma unroll
  for (int p = 0; p < 2; ++p) {
    int cl = cbase + p * 16 + l16;
    pbh0[p] = *(const bf16x8*)(chi + cl * 64 + bko);
    pbh1[p] = *(const bf16x8*)(chi + cl * 64 + 32 + bko);
    pbl0[p] = *(const bf16x8*)(clo + cl * 64 + bko);
    pbl1[p] = *(const bf16x8*)(clo + cl * 64 + 32 + bko);
    pcs4[p] = *(const f32x4*)(csqs + cbase + p * 16 + quad * 4);
  }

  const unsigned swz = ((unsigned)(l16 & 7)) << 3;   // row&7 == l16&7

#pragma unroll
  for (int t = 0; t < 8; ++t) {
    const int sl = t & 1;
    bf16x8 cbh0 = pbh0[sl], cbh1 = pbh1[sl], cbl0 = pbl0[sl], cbl1 = pbl1[sl];
    f32x4 csq4 = pcs4[sl];
    if (t < 6) {   // prefetch t+2
      int cl = cbase + (t + 2) * 16 + l16;
      pbh0[sl] = *(const bf16x8*)(chi + cl * 64 + bko);
      pbh1[sl] = *(const bf16x8*)(chi + cl * 64 + 32 + bko);
      pbl0[sl] = *(const bf16x8*)(clo + cl * 64 + bko);
      pbl1[sl] = *(const bf16x8*)(clo + cl * 64 + 32 + bko);
      pcs4[sl] = *(const f32x4*)(csqs + cbase + (t + 2) * 16 + quad * 4);
    }
    const int c0 = cbase + t * 16 + quad * 4;
    // 24 MFMAs (swapped operands: D[m=cluster(quad*4+r)][n=row(l16)])
    f32x4 av[4];
#pragma unroll
    for (int rt = 0; rt < 4; ++rt) {
      f32x4 a_hi = {0.f, 0.f, 0.f, 0.f};
      f32x4 a_lo = {0.f, 0.f, 0.f, 0.f};
      a_hi = __builtin_amdgcn_mfma_f32_16x16x32_bf16(cbh0, ah[rt][0], a_hi, 0, 0, 0);
      a_lo = __builtin_amdgcn_mfma_f32_16x16x32_bf16(cbh0, al[rt][0], a_lo, 0, 0, 0);
      a_hi = __builtin_amdgcn_mfma_f32_16x16x32_bf16(cbh1, ah[rt][1], a_hi, 0, 0, 0);
      a_lo = __builtin_amdgcn_mfma_f32_16x16x32_bf16(cbh1, al[rt][1], a_lo, 0, 0, 0);
      a_hi = __builtin_amdgcn_mfma_f32_16x16x32_bf16(cbl0, ah[rt][0], a_hi, 0, 0, 0);
      a_hi = __builtin_amdgcn_mfma_f32_16x16x32_bf16(cbl1, ah[rt][1], a_hi, 0, 0, 0);
      av[rt] = a_hi + a_lo;
    }
    // exp tail: v_exp + cvt_pk pairs, ONE b64 store per rt
#pragma unroll
    for (int rt = 0; rt < 4; ++rt) {
      float e0 = vexp2(fmaf(28.85390081777927f, av[rt][0], -csq4[0]));
      float e1 = vexp2(fmaf(28.85390081777927f, av[rt][1], -csq4[1]));
      float e2 = vexp2(fmaf(28.85390081777927f, av[rt][2], -csq4[2]));
      float e3 = vexp2(fmaf(28.85390081777927f, av[rt][3], -csq4[3]));
      uint2 wp;
      wp.x = cvtpk_bf16(e0, e1);
      wp.y = cvtpk_bf16(e2, e3);
      *(uint2*)(W + (rt * 16 + l16) * 512 + ((unsigned)c0 ^ swz)) = wp;
    }
  }

  // ---- Phase C B prefetch, depth 4, issued before the barrier ----
  const int feat = wv * 16 + l16;
  const unsigned short* cth = cthi + feat * K_CLUSTERS;
  bf16x8 qbh[4];
#pragma unroll
  for (int p = 0; p < 4; ++p)
    qbh[p] = *(const bf16x8*)(cth + p * 32 + quad * 8);
  bf16x8 ones;
#pragma unroll
  for (int j = 0; j < 8; ++j) ones[j] = (short)0x3F80;

  __syncthreads();   // W visible to all waves

  // ---- Phase C: wave's 16-feature slice, full K=512, hi-only PV.
  // 8 independent chains: oh[4] (W*C), os[4] (row sums via ones-B).
  f32x4 oh[4] = {{0.f,0.f,0.f,0.f},{0.f,0.f,0.f,0.f},{0.f,0.f,0.f,0.f},{0.f,0.f,0.f,0.f}};
  f32x4 os[4] = {{0.f,0.f,0.f,0.f},{0.f,0.f,0.f,0.f},{0.f,0.f,0.f,0.f},{0.f,0.f,0.f,0.f}};

#pragma unroll
  for (int ks = 0; ks < 16; ++ks) {
    const int sl = ks & 3;
    bf16x8 bh = qbh[sl];
    if (ks < 12)   // prefetch ks+4
      qbh[sl] = *(const bf16x8*)(cth + (ks + 4) * 32 + quad * 8);
    const int ac = ks * 32 + quad * 8;
    bf16x8 aw[4];
#pragma unroll
    for (int rt = 0; rt < 4; ++rt) {
      int arow = rt * 16 + l16;
      aw[rt] = *(const bf16x8*)(W + arow * 512 + ((unsigned)ac ^ WSWZ(arow)));
    }
#pragma unroll
    for (int rt = 0; rt < 4; ++rt) {
      oh[rt] = __builtin_amdgcn_mfma_f32_16x16x32_bf16(aw[rt], bh, oh[rt], 0, 0, 0);
      os[rt] = __builtin_amdgcn_mfma_f32_16x16x32_bf16(aw[rt], ones, os[rt], 0, 0, 0);
    }
  }

  // ---- epilogue: normalize by MFMA row sums (layout-aligned, no shuffles) ----
#pragma unroll
  for (int rt = 0; rt < 4; ++rt) {
    float* obase = out + (rowbase + rt * 16) * D_FEAT + feat;
#pragma unroll
    for (int r = 0; r < 4; ++r) {
      float val = oh[rt][r] * __builtin_amdgcn_rcpf(os[rt][r]);
      obase[(quad * 4 + r) * D_FEAT] = val;
    }
  }
}

extern "C" void kernel_launch(void* const* d_in, const int* in_sizes, int n_in,
                              void* d_out, int out_size, void* d_ws, size_t ws_size,
                              hipStream_t stream) {
  const float* x    = (const float*)d_in[0];
  const float* cent = (const float*)d_in[1];
  float* out        = (float*)d_out;

  unsigned short* chi  = (unsigned short*)d_ws;
  unsigned short* clo  = chi  + K_CLUSTERS * D_FEAT;
  unsigned short* cthi = clo  + K_CLUSTERS * D_FEAT;
  float*          csqs = (float*)(cthi + K_CLUSTERS * D_FEAT);

  kmeans_prep<<<K_CLUSTERS / 4, 256, 0, stream>>>(
      cent, chi, clo, cthi, csqs);

  int nrows = in_sizes[0] / D_FEAT;  // 131072
  kmeans_main<<<nrows / ROWS_PER_BLOCK, THREADS, 0, stream>>>(
      x, chi, clo, cthi, csqs, out);
}